// Round 12
// baseline (821.981 us; speedup 1.0000x reference)
//
#include <hip/hip_runtime.h>
#include <hip/hip_bf16.h>
#include <math.h>

// ---------- types ----------
typedef __bf16 bf16x8 __attribute__((ext_vector_type(8)));
typedef float  f32x4  __attribute__((ext_vector_type(4)));

struct __align__(8) bf16x4s { __hip_bfloat16 a, b, c, d; };

__device__ __forceinline__ void gload_lds16(const void* g, void* l) {
  __builtin_amdgcn_global_load_lds(
      (const __attribute__((address_space(1))) void*)g,
      (__attribute__((address_space(3))) void*)l, 16, 0, 0);
}

__device__ __forceinline__ float fast_gelu(float v) {
  // gelu(v) = 0.5 v (1 + erf(v/sqrt2)), erf via A&S 7.1.26 (|err|<=1.5e-7), branchless
  float s = 0.70710678118654752f * v;
  float a = fabsf(s);
  float t = __builtin_amdgcn_rcpf(fmaf(0.3275911f, a, 1.0f));
  float p = t * fmaf(t, fmaf(t, fmaf(t, fmaf(t, 1.061405429f, -1.453152027f),
                                     1.421413741f), -0.284496736f), 0.254829592f);
  float e = __expf(-a * a);
  float er = copysignf(fmaf(-p, e, 1.0f), s);
  return 0.5f * v * (1.0f + er);
}

#define BAR()   asm volatile("s_barrier" ::: "memory")
#define LGKM0() do { asm volatile("s_waitcnt lgkmcnt(0)" ::: "memory"); \
                     __builtin_amdgcn_sched_barrier(0); } while (0)
#define VMC(N)  do { asm volatile("s_waitcnt vmcnt(" #N ")" ::: "memory"); \
                     __builtin_amdgcn_sched_barrier(0); } while (0)
#define P1()    __builtin_amdgcn_s_setprio(1)
#define P0()    __builtin_amdgcn_s_setprio(0)

// one C-quadrant x K=64: MB in {0,4}, NB in {0,2} are LITERAL tokens (static acc idx)
#define MQ(MB, NB, AV, BV)                                                    \
  do {                                                                        \
    _Pragma("unroll")                                                         \
    for (int mi_ = 0; mi_ < 4; ++mi_)                                         \
      _Pragma("unroll")                                                       \
      for (int nj_ = 0; nj_ < 2; ++nj_)                                       \
        _Pragma("unroll")                                                     \
        for (int kk_ = 0; kk_ < 2; ++kk_)                                     \
          acc[MB + mi_][NB + nj_] = __builtin_amdgcn_mfma_f32_16x16x32_bf16(  \
              AV[mi_][kk_], BV[nj_][kk_], acc[MB + mi_][NB + nj_], 0, 0, 0);  \
  } while (0)

// ---------- GEMM: C[M,N] = A[M,K](bf16,row) * B[N,K]^T(bf16,row) ----------
// LDS-BW-bound fix (r12): B operand goes GLOBAL -> REGISTERS directly
// (per-wave-exclusive 64-row panel, contiguous 16B fragments, no swizzle),
// double-buffered one K-tile ahead; compiler tracks its vmcnt/register deps.
// LDS carries A only (2 x 32 KB bufs): traffic/K-tile 256KB -> 160KB.
// A-path (stage swizzle + readAE/AL) identical to r11. Ledger: per K-tile
// {MFMA-E; readAL; MFMA-L; LGKM0; BAR; stageA(s+2); VMC(12); BAR; readAE(next)}.
// Issue order [.., A(s+1)4, B(s+1)8, A(s+2)4] => VMC(12) gates A(s+1); tail VMC(8).
// EPI 0: u1' = bf16( W[b,p] * gelu(acc + b1[p,e]) )   (p=n>>10, b=m>>5)
// EPI 2: f32out[m*N + n] = acc
// EPI 4: bfout[slab + m*N + n] = bf16(acc)            (split-K partials)
template<int EPI>
__global__ __launch_bounds__(512, 2)
void gemm_nt(const __hip_bfloat16* __restrict__ A,
             const __hip_bfloat16* __restrict__ B,
             const int K, const int Kc, const int N,
             const float* __restrict__ p0,   // EPI0: b1[P,1024]
             const float* __restrict__ p1,   // EPI0: W[B,P] (this depth)
             float* __restrict__ f32out,
             __hip_bfloat16* __restrict__ bfout) // EPI0: u1, EPI4: partials
{
  __shared__ __align__(16) __hip_bfloat16 lds[32768];  // A only: 2 bufs x 256x64

  const int tid = threadIdx.x;
  const int lane = tid & 63, wid = tid >> 6;
  const int l15 = lane & 15, l4 = lane >> 4;
  const int r8 = lane >> 3, blk = lane & 7;
  const int wm = wid >> 2, wn = wid & 3;   // 2 x 4 wave grid

  // XCD-aware chunked swizzle (nwg % 8 == 0 for all grids used here)
  const int nx = gridDim.x;
  const int flat = blockIdx.x + nx * blockIdx.y;
  const int q = (nx * gridDim.y) >> 3;
  const int nid = (flat & 7) * q + (flat >> 3);
  const long m0 = (long)(nid % nx) * 256;
  const long n0 = (long)(nid / nx) * 256;

  const int kbeg = blockIdx.z * Kc;
  const int nt = Kc / 64;

  f32x4 acc[8][4] = {};
  bf16x8 ar[4][2];                       // single A frag set (E, then L reuse)
  bf16x8 b0E[2][2], b0L[2][2], b1E[2][2], b1L[2][2];  // B double buffer

  // stage full A K-tile (256x64 = 32 KB, 4 gload_lds16/thread); src pre-XOR-swizzled
  auto stageA2 = [&](int buf, int k0) {
#pragma unroll
    for (int p2 = 0; p2 < 4; ++p2) {
      int ch = p2 * 8 + wid;
      int row = ch * 8 + r8;
      gload_lds16(A + (m0 + row) * (long)K + k0 + ((blk ^ r8) << 3),
                  lds + buf * 16384 + ch * 512);
    }
  };
  // B fragments straight from global (per-wave panel; contiguous 16B per lane)
  auto loadB = [&](bf16x8 (&bE)[2][2], bf16x8 (&bL)[2][2], int k0) {
#pragma unroll
    for (int nj = 0; nj < 2; ++nj)
#pragma unroll
      for (int kk = 0; kk < 2; ++kk) {
        bE[nj][kk] = *(const bf16x8*)(B + (n0 + wn * 64 + nj * 16 + l15) * (long)K
                                        + k0 + kk * 32 + l4 * 8);
        bL[nj][kk] = *(const bf16x8*)(B + (n0 + wn * 64 + 32 + nj * 16 + l15) * (long)K
                                        + k0 + kk * 32 + l4 * 8);
      }
  };
  // A register loads (XOR-swizzled ds_read_b128) into ar
  auto readAE = [&](int buf) {
    const __hip_bfloat16* pA = lds + buf * 16384;
#pragma unroll
    for (int mi = 0; mi < 4; ++mi)
#pragma unroll
      for (int kk = 0; kk < 2; ++kk) {
        int row = wm * 128 + mi * 16 + l15;
        ar[mi][kk] = *(const bf16x8*)(pA + row * 64 + (((kk * 4 + l4) ^ (row & 7)) << 3));
      }
  };
  auto readAL = [&](int buf) {
    const __hip_bfloat16* pA = lds + buf * 16384;
#pragma unroll
    for (int mi = 0; mi < 4; ++mi)
#pragma unroll
      for (int kk = 0; kk < 2; ++kk) {
        int row = wm * 128 + 64 + mi * 16 + l15;
        ar[mi][kk] = *(const bf16x8*)(pA + row * 64 + (((kk * 4 + l4) ^ (row & 7)) << 3));
      }
  };

  // ---- prologue: A0 ; B0 ; A1 ; gate A0 (8+4 after it) ; first A-E frags ----
  stageA2(0, kbeg);
  loadB(b0E, b0L, kbeg);
  stageA2(1, kbeg + 64);
  VMC(12);
  BAR();
  readAE(0);

  // ---- main loop: iteration t = tiles 2t (buf0,B0) and 2t+1 (buf1,B1) ----
  const int nit = nt >> 1;
  for (int t = 0; t < nit - 1; ++t) {
    // tile 2t
    loadB(b1E, b1L, kbeg + (2 * t + 1) * 64);       // B(2t+1) -> regs
    P1(); MQ(0, 0, ar, b0E); MQ(0, 2, ar, b0L); P0();
    readAL(0);                                       // ar <- A-late (after E use)
    P1(); MQ(4, 0, ar, b0E); MQ(4, 2, ar, b0L); P0();
    LGKM0();                                         // all reads of buf0 retired
    BAR();
    stageA2(0, kbeg + (2 * t + 2) * 64);             // A(2t+2) -> buf0
    VMC(12);                                         // A(2t+1) landed (own wave)
    BAR();                                           // ... collectively
    readAE(1);
    // tile 2t+1
    loadB(b0E, b0L, kbeg + (2 * t + 2) * 64);       // B(2t+2) -> regs
    P1(); MQ(0, 0, ar, b1E); MQ(0, 2, ar, b1L); P0();
    readAL(1);
    P1(); MQ(4, 0, ar, b1E); MQ(4, 2, ar, b1L); P0();
    LGKM0();
    BAR();
    stageA2(1, kbeg + (2 * t + 3) * 64);             // A(2t+3) -> buf1
    VMC(12);                                         // A(2t+2) landed
    BAR();
    readAE(0);
  }

  // ---- tail: tiles nt-2 (buf0,B0) and nt-1 (buf1,B1); no more stages ----
  loadB(b1E, b1L, kbeg + (nt - 1) * 64);
  P1(); MQ(0, 0, ar, b0E); MQ(0, 2, ar, b0L); P0();
  readAL(0);
  P1(); MQ(4, 0, ar, b0E); MQ(4, 2, ar, b0L); P0();
  VMC(8);                                            // A(nt-1): only B(nt-1)8 after it
  BAR();                                             // collective
  readAE(1);
  P1(); MQ(0, 0, ar, b1E); MQ(0, 2, ar, b1L); P0();
  readAL(1);
  P1(); MQ(4, 0, ar, b1E); MQ(4, 2, ar, b1L); P0();

  // epilogue: D[row=(l>>4)*4+r][col=l&15] per 16x16 frag (m89-verified layout)
  const long slab = (EPI == 4) ? (long)blockIdx.z * (long)(gridDim.x * 256) * N : 0;
#pragma unroll
  for (int mi = 0; mi < 8; ++mi) {
    const long gmb = m0 + wm * 128 + mi * 16 + l4 * 4;   // rows gmb..gmb+3 (same batch b)
    const int b = (int)(gmb >> 5);
#pragma unroll
    for (int nj = 0; nj < 4; ++nj) {
      const long gn = n0 + wn * 64 + nj * 16 + l15;
      if constexpr (EPI == 0) {
        const int p = (int)(gn >> 10), e = (int)(gn & 1023);
        const float bias = p0[(p << 10) + e];
        const float wpb = p1[(b << 3) + p];
#pragma unroll
        for (int r = 0; r < 4; ++r) {
          float v = fast_gelu(acc[mi][nj][r] + bias) * wpb;
          bfout[(gmb + r) * (long)N + gn] = __float2bfloat16(v);
        }
      } else if constexpr (EPI == 2) {
#pragma unroll
        for (int r = 0; r < 4; ++r)
          f32out[(gmb + r) * (long)N + gn] = acc[mi][nj][r];
      } else {
#pragma unroll
        for (int r = 0; r < 4; ++r)
          bfout[slab + (gmb + r) * (long)N + gn] = __float2bfloat16(acc[mi][nj][r]);
      }
    }
  }
}

// ---------- small kernels ----------
__global__ void cvt_bf16_k(const float* __restrict__ in, __hip_bfloat16* __restrict__ out, long n) {
  long i = ((long)blockIdx.x * blockDim.x + threadIdx.x) * 4;
  if (i >= n) return;
  float4 v = *(const float4*)(in + i);
  *(bf16x4s*)(out + i) = bf16x4s{__float2bfloat16(v.x), __float2bfloat16(v.y),
                                 __float2bfloat16(v.z), __float2bfloat16(v.w)};
}

// out[c*out_rs + p*out_bs + r] = bf16(in[p*in_bs + r*1024 + c]), tiles of 32x32
__global__ void tconv_k(const float* __restrict__ in, __hip_bfloat16* __restrict__ out,
                        long in_bs, long out_rs, long out_bs) {
  __shared__ float tile[32][33];
  int p = blockIdx.z;
  int r0 = blockIdx.y * 32, c0 = blockIdx.x * 32;
  int tx = threadIdx.x, ty = threadIdx.y;
#pragma unroll
  for (int i = 0; i < 32; i += 8)
    tile[ty + i][tx] = in[(long)p * in_bs + (long)(r0 + ty + i) * 1024 + c0 + tx];
  __syncthreads();
#pragma unroll
  for (int i = 0; i < 32; i += 8)
    out[(long)(c0 + ty + i) * out_rs + (long)p * out_bs + (r0 + tx)] =
        __float2bfloat16(tile[tx][ty + i]);
}

__global__ void embed_k(const int* __restrict__ x, const float* __restrict__ emb,
                        const float* __restrict__ pos, float* __restrict__ h,
                        __hip_bfloat16* __restrict__ hb, float* __restrict__ divp) {
  int row = blockIdx.x;          // b*32 + t
  int t = row & 31;
  int c = threadIdx.x * 4;
  long tok = x[row];
  float4 e = *(const float4*)(emb + tok * 1024 + c);
  float4 q = *(const float4*)(pos + (long)t * 1024 + c);
  float4 v{e.x + q.x, e.y + q.y, e.z + q.z, e.w + q.w};
  *(float4*)(h + (long)row * 1024 + c) = v;
  *(bf16x4s*)(hb + (long)row * 1024 + c) =
      bf16x4s{__float2bfloat16(v.x), __float2bfloat16(v.y),
              __float2bfloat16(v.z), __float2bfloat16(v.w)};
  if (row == 0 && threadIdx.x == 0) *divp = 0.f;
}

// fused: selector softmax (-> W[dep]) + wb2[b,:] = sum_p W[b,p]*b2[p,:]
__global__ void select_wb2_k(const float* __restrict__ h, const float* __restrict__ selw,
                             const float* __restrict__ selb, const float* __restrict__ gum,
                             const float* __restrict__ b2, float* __restrict__ W,
                             float* __restrict__ wb2, int dep) {
  int b = blockIdx.x, tid = threadIdx.x;
  int c = tid * 4;
  float4 s{0.f, 0.f, 0.f, 0.f};
  for (int t = 0; t < 32; ++t) {
    const float4 v = *(const float4*)(h + ((long)(b * 32 + t)) * 1024 + c);
    s.x += v.x; s.y += v.y; s.z += v.z; s.w += v.w;
  }
  float lp[8];
#pragma unroll
  for (int p = 0; p < 8; ++p) {
    const float4 w = *(const float4*)(selw + dep * 8192 + p * 1024 + c);
    lp[p] = (s.x * w.x + s.y * w.y + s.z * w.z + s.w * w.w) * (1.f / 32.f);
  }
  int lane = tid & 63, wid = tid >> 6;
#pragma unroll
  for (int p = 0; p < 8; ++p)
    for (int o = 32; o; o >>= 1) lp[p] += __shfl_down(lp[p], o);
  __shared__ float red[4][8];
  __shared__ float wsm[8];
  if (lane == 0) {
#pragma unroll
    for (int p = 0; p < 8; ++p) red[wid][p] = lp[p];
  }
  __syncthreads();
  if (tid == 0) {
    float lg[8], mx = -1e30f;
    for (int p = 0; p < 8; ++p) {
      lg[p] = red[0][p] + red[1][p] + red[2][p] + red[3][p]
            + selb[dep * 8 + p] + gum[dep * 512 + b * 8 + p];
      mx = fmaxf(mx, lg[p]);
    }
    float sm = 0.f;
    for (int p = 0; p < 8; ++p) { lg[p] = expf(lg[p] - mx); sm += lg[p]; }
    float inv = 1.f / sm;
    for (int p = 0; p < 8; ++p) { wsm[p] = lg[p] * inv; W[dep * 512 + b * 8 + p] = lg[p] * inv; }
  }
  __syncthreads();
  float4 a{0.f, 0.f, 0.f, 0.f};
#pragma unroll
  for (int p = 0; p < 8; ++p) {
    float wp = wsm[p];
    const float4 v = *(const float4*)(b2 + p * 1024 + c);
    a.x += wp * v.x; a.y += wp * v.y; a.z += wp * v.z; a.w += wp * v.w;
  }
  *(float4*)(wb2 + (long)b * 1024 + c) = a;
}

// h += wb2 + sum_s part[s] (8 bf16 split-K slabs); write h f32 + bf16.
// block 0 lanes 0..63 also fold this depth's KL term into divp (wave-parallel).
__global__ void h_update_k(const __hip_bfloat16* __restrict__ part, float* __restrict__ h,
                           const float* __restrict__ wb2, __hip_bfloat16* __restrict__ hb,
                           const float* __restrict__ Wd, float* __restrict__ divp) {
  int row = blockIdx.x;
  int c = threadIdx.x * 4;
  long idx = (long)row * 1024 + c;
  float4 a = *(const float4*)(h + idx);
  const float4 w = *(const float4*)(wb2 + (long)(row >> 5) * 1024 + c);
  a.x += w.x; a.y += w.y; a.z += w.z; a.w += w.w;
#pragma unroll
  for (int s = 0; s < 8; ++s) {
    const bf16x4s v = *(const bf16x4s*)(part + (long)s * 2097152 + idx);
    a.x += __bfloat162float(v.a); a.y += __bfloat162float(v.b);
    a.z += __bfloat162float(v.c); a.w += __bfloat162float(v.d);
  }
  *(float4*)(h + idx) = a;
  *(bf16x4s*)(hb + idx) = bf16x4s{__float2bfloat16(a.x), __float2bfloat16(a.y),
                                  __float2bfloat16(a.z), __float2bfloat16(a.w)};
  if (blockIdx.x == 0 && threadIdx.x < 64) {
    float w8[8];
#pragma unroll
    for (int p = 0; p < 8; ++p) w8[p] = Wd[threadIdx.x * 8 + p];
#pragma unroll
    for (int p = 0; p < 8; ++p)
      for (int o = 32; o; o >>= 1) w8[p] += __shfl_down(w8[p], o);
    if (threadIdx.x == 0) {
      float d = *divp;
      const float u = 0.125f, lu = logf(0.125f);
#pragma unroll
      for (int p = 0; p < 8; ++p) d += u * (lu - logf(w8[p] * (1.f / 64.f)));
      *divp = d;
    }
  }
}

__global__ void ln_k(const float* __restrict__ h, const float* __restrict__ g,
                     const float* __restrict__ be, __hip_bfloat16* __restrict__ hnb,
                     const float* __restrict__ divp, float* __restrict__ divout) {
  int row = blockIdx.x, tid = threadIdx.x;
  int c = tid * 4;
  const float4 v = *(const float4*)(h + (long)row * 1024 + c);
  float s = v.x + v.y + v.z + v.w;
  float q = v.x * v.x + v.y * v.y + v.z * v.z + v.w * v.w;
  for (int o = 32; o; o >>= 1) { s += __shfl_down(s, o); q += __shfl_down(q, o); }
  __shared__ float red[16];
  int lane = tid & 63, wid = tid >> 6;
  if (lane == 0) { red[wid] = s; red[8 + wid] = q; }
  __syncthreads();
  if (tid == 0) {
    float S = red[0] + red[1] + red[2] + red[3];
    float Q = red[8] + red[9] + red[10] + red[11];
    float mu = S * (1.f / 1024.f);
    float var = Q * (1.f / 1024.f) - mu * mu;
    red[0] = mu; red[1] = rsqrtf(var + 1e-5f);
  }
  __syncthreads();
  float mu = red[0], rs = red[1];
  float4 gg = *(const float4*)(g + c), bb = *(const float4*)(be + c);
  *(bf16x4s*)(hnb + (long)row * 1024 + c) =
      bf16x4s{__float2bfloat16((v.x - mu) * rs * gg.x + bb.x),
              __float2bfloat16((v.y - mu) * rs * gg.y + bb.y),
              __float2bfloat16((v.z - mu) * rs * gg.z + bb.z),
              __float2bfloat16((v.w - mu) * rs * gg.w + bb.w)};
  if (row == 0 && tid == 0) *divout = *divp;
}

// ---------- launch ----------
extern "C" void kernel_launch(void* const* d_in, const int* in_sizes, int n_in,
                              void* d_out, int out_size, void* d_ws, size_t ws_size,
                              hipStream_t stream) {
  (void)in_sizes; (void)n_in; (void)out_size; (void)ws_size;
  const int*   x     = (const int*)  d_in[0];
  const float* emb   = (const float*)d_in[1];
  const float* pos   = (const float*)d_in[2];
  const float* w1    = (const float*)d_in[3];
  const float* b1    = (const float*)d_in[4];
  const float* w2    = (const float*)d_in[5];
  const float* b2    = (const float*)d_in[6];
  const float* selw  = (const float*)d_in[7];
  const float* selb  = (const float*)d_in[8];
  const float* lng   = (const float*)d_in[9];
  const float* lnb   = (const float*)d_in[10];
  const float* headw = (const float*)d_in[11];
  const float* gum   = (const float*)d_in[12];
  float* out = (float*)d_out;

  char* ws = (char*)d_ws;
  __hip_bfloat16* w1t   = (__hip_bfloat16*)(ws);               // [8192,1024] bf16  16 MiB
  __hip_bfloat16* w2t   = (__hip_bfloat16*)(ws + 16777216);    // [1024,8192] bf16  16 MiB
  __hip_bfloat16* headb = (__hip_bfloat16*)(ws + 33554432);    // [32000,1024] bf16 62.5 MiB
  float*          h     = (float*)(ws + 99090432);             // [2048,1024] f32   8 MiB
  __hip_bfloat16* hb    = (__hip_bfloat16*)(ws + 107479040);   // [2048,1024] bf16  4 MiB
  __hip_bfloat16* u1    = (__hip_bfloat16*)(ws + 111673344);   // [2048,8192] bf16  32 MiB
  float*          Wall  = (float*)(ws + 145227776);            // [4,64,8]
  float*          wb2   = (float*)(ws + 145240064);            // [64,1024]
  float*          divp  = (float*)(ws + 145502208);            // scalar
  __hip_bfloat16* part  = (__hip_bfloat16*)out;  // GEMM2 bf16 partials: 8 x [2048,1024]
                                                 // = 32 MiB scratch inside d_out (262 MiB),
                                                 // overwritten by the head GEMM later

  cvt_bf16_k<<<32000, 256, 0, stream>>>(headw, headb, 32768000L);
  tconv_k<<<dim3(32, 32, 8), dim3(32, 8), 0, stream>>>(w1, w1t, 1L << 20, 1024L, 1L << 20);
  tconv_k<<<dim3(32, 32, 8), dim3(32, 8), 0, stream>>>(w2, w2t, 1L << 20, 8192L, 1024L);
  embed_k<<<2048, 256, 0, stream>>>(x, emb, pos, h, hb, divp);

  for (int d = 0; d < 4; ++d) {
    select_wb2_k<<<64, 256, 0, stream>>>(h, selw, selb, gum, b2, Wall, wb2, d);
    // u1' = W * gelu(h @ w1 + b1)   : M=2048 N=8192 K=1024  (8x32 = 256 blocks, 1/CU)
    gemm_nt<0><<<dim3(8, 32), 512, 0, stream>>>(hb, w1t, 1024, 1024, 8192, b1, Wall + d * 512, nullptr, u1);
    // partials[z] = bf16(u1' @ w2, K chunk z) : M=2048 N=1024 K=8192, split-K x8 (256 blocks)
    gemm_nt<4><<<dim3(8, 4, 8), 512, 0, stream>>>(u1, w2t, 8192, 1024, 1024, nullptr, nullptr, nullptr, part);
    h_update_k<<<2048, 256, 0, stream>>>(part, h, wb2, hb, Wall + d * 512, divp);
  }

  ln_k<<<2048, 256, 0, stream>>>(h, lng, lnb, hb, divp, out + 65536000L);
  // logits = hn @ head_w^T          : M=2048 N=32000 K=1024  (8x125 = 1000 blocks)
  gemm_nt<2><<<dim3(8, 125), 512, 0, stream>>>(hb, headb, 1024, 1024, 32000, nullptr, nullptr, out, nullptr);
}

// Round 13
// 606.917 us; speedup vs baseline: 1.3544x; 1.3544x over previous
//
#include <hip/hip_runtime.h>
#include <hip/hip_bf16.h>
#include <math.h>

// ---------- types ----------
typedef __bf16 bf16x8 __attribute__((ext_vector_type(8)));
typedef float  f32x4  __attribute__((ext_vector_type(4)));

struct __align__(8) bf16x4s { __hip_bfloat16 a, b, c, d; };

__device__ __forceinline__ void gload_lds16(const void* g, void* l) {
  __builtin_amdgcn_global_load_lds(
      (const __attribute__((address_space(1))) void*)g,
      (__attribute__((address_space(3))) void*)l, 16, 0, 0);
}

__device__ __forceinline__ float fast_gelu(float v) {
  // gelu(v) = 0.5 v (1 + erf(v/sqrt2)), erf via A&S 7.1.26 (|err|<=1.5e-7), branchless
  float s = 0.70710678118654752f * v;
  float a = fabsf(s);
  float t = __builtin_amdgcn_rcpf(fmaf(0.3275911f, a, 1.0f));
  float p = t * fmaf(t, fmaf(t, fmaf(t, fmaf(t, 1.061405429f, -1.453152027f),
                                     1.421413741f), -0.284496736f), 0.254829592f);
  float e = __expf(-a * a);
  float er = copysignf(fmaf(-p, e, 1.0f), s);
  return 0.5f * v * (1.0f + er);
}

#define BAR()   asm volatile("s_barrier" ::: "memory")
#define LGKM0() do { asm volatile("s_waitcnt lgkmcnt(0)" ::: "memory"); \
                     __builtin_amdgcn_sched_barrier(0); } while (0)
#define LGKM8() do { asm volatile("s_waitcnt lgkmcnt(8)" ::: "memory"); \
                     __builtin_amdgcn_sched_barrier(0); } while (0)
#define VMC(N)  do { asm volatile("s_waitcnt vmcnt(" #N ")" ::: "memory"); \
                     __builtin_amdgcn_sched_barrier(0); } while (0)
#define P1()    __builtin_amdgcn_s_setprio(1)
#define P0()    __builtin_amdgcn_s_setprio(0)

// one C-quadrant x K=64: MB in {0,4}, NB in {0,2} are LITERAL tokens (static acc idx)
#define MQ(MB, NB, AV, BV)                                                    \
  do {                                                                        \
    _Pragma("unroll")                                                         \
    for (int mi_ = 0; mi_ < 4; ++mi_)                                         \
      _Pragma("unroll")                                                       \
      for (int nj_ = 0; nj_ < 2; ++nj_)                                       \
        _Pragma("unroll")                                                     \
        for (int kk_ = 0; kk_ < 2; ++kk_)                                     \
          acc[MB + mi_][NB + nj_] = __builtin_amdgcn_mfma_f32_16x16x32_bf16(  \
              AV[mi_][kk_], BV[nj_][kk_], acc[MB + mi_][NB + nj_], 0, 0, 0);  \
  } while (0)

// ---------- GEMM: C[M,N] = A[M,K](bf16,row) * B[N,K]^T(bf16,row) ----------
// r11's validated 8-phase template (m201 port): 2 K-tiles per iteration with
// compile-time buffer indices, per phase {ds_read subtile ; stage 1 half-tile ;
// [lgkmcnt(8) if 12 reads] ; barrier ; lgkmcnt(0) ; setprio(1) 16 MFMA
// setprio(0) ; [vmcnt(6) at phases 4/8] ; barrier}.  16x16x32 MFMA.
// (r10: 32x32 shape regressed - fragment addressing 4-way LDS aliasing.
//  r12: B-direct-to-regs regressed - 4 B frag sets blew the VGPR budget.)
// EPI 0: u1' = bf16( W[b,p] * gelu(acc + b1[p,e]) )   (p=n>>10, b=m>>5)
// EPI 2: f32out[m*N + n] = acc
// EPI 4: bfout[slab + m*N + n] = bf16(acc)            (split-K partials)
template<int EPI>
__global__ __launch_bounds__(512, 2)
void gemm_nt(const __hip_bfloat16* __restrict__ A,
             const __hip_bfloat16* __restrict__ B,
             const int K, const int Kc, const int N,
             const float* __restrict__ p0,   // EPI0: b1[P,1024]
             const float* __restrict__ p1,   // EPI0: W[B,P] (this depth)
             float* __restrict__ f32out,
             __hip_bfloat16* __restrict__ bfout) // EPI0: u1, EPI4: partials
{
  __shared__ __align__(16) __hip_bfloat16 lds[65536];

  const int tid = threadIdx.x;
  const int lane = tid & 63, wid = tid >> 6;
  const int l15 = lane & 15, l4 = lane >> 4;
  const int r8 = lane >> 3, blk = lane & 7;
  const int wm = wid >> 2, wn = wid & 3;   // 2 x 4 wave grid

  // XCD-aware chunked swizzle (nwg % 8 == 0 for all grids used here)
  const int nx = gridDim.x;
  const int flat = blockIdx.x + nx * blockIdx.y;
  const int q = (nx * gridDim.y) >> 3;
  const int nid = (flat & 7) * q + (flat >> 3);
  const long m0 = (long)(nid % nx) * 256;
  const long n0 = (long)(nid / nx) * 256;

  const int kbeg = blockIdx.z * Kc;
  const int nt = Kc / 64;

  f32x4 acc[8][4] = {};
  bf16x8 arE[4][2], arL[4][2], brE[2][2], brL[2][2];

  // stage one half-tile (16 KB, 2 gload_lds16/thread); global src pre-XOR-swizzled
  auto stageA = [&](int buf, int h, int k0) {
#pragma unroll
    for (int p2 = 0; p2 < 2; ++p2) {
      int ch = p2 * 16 + h * 8 + wid;
      int row = ch * 8 + r8;
      gload_lds16(A + (m0 + row) * (long)K + k0 + ((blk ^ r8) << 3),
                  lds + buf * 16384 + ch * 512);
    }
  };
  auto stageB = [&](int buf, int h, int k0) {
#pragma unroll
    for (int p2 = 0; p2 < 2; ++p2) {
      int ch = (p2 * 2 + (wid >> 2)) * 8 + h * 4 + (wid & 3);
      int row = ch * 8 + r8;
      gload_lds16(B + (n0 + row) * (long)K + k0 + ((blk ^ r8) << 3),
                  lds + 32768 + buf * 16384 + ch * 512);
    }
  };
  // register loads (XOR-swizzled ds_read_b128); buf passed as literal -> static addrs
  auto readAE = [&](int buf) {
    const __hip_bfloat16* pA = lds + buf * 16384;
#pragma unroll
    for (int mi = 0; mi < 4; ++mi)
#pragma unroll
      for (int kk = 0; kk < 2; ++kk) {
        int row = wm * 128 + mi * 16 + l15;
        arE[mi][kk] = *(const bf16x8*)(pA + row * 64 + (((kk * 4 + l4) ^ (row & 7)) << 3));
      }
  };
  auto readAL = [&](int buf) {
    const __hip_bfloat16* pA = lds + buf * 16384;
#pragma unroll
    for (int mi = 0; mi < 4; ++mi)
#pragma unroll
      for (int kk = 0; kk < 2; ++kk) {
        int row = wm * 128 + 64 + mi * 16 + l15;
        arL[mi][kk] = *(const bf16x8*)(pA + row * 64 + (((kk * 4 + l4) ^ (row & 7)) << 3));
      }
  };
  auto readBE = [&](int buf) {
    const __hip_bfloat16* pB = lds + 32768 + buf * 16384;
#pragma unroll
    for (int nj = 0; nj < 2; ++nj)
#pragma unroll
      for (int kk = 0; kk < 2; ++kk) {
        int row = wn * 64 + nj * 16 + l15;
        brE[nj][kk] = *(const bf16x8*)(pB + row * 64 + (((kk * 4 + l4) ^ (row & 7)) << 3));
      }
  };
  auto readBL = [&](int buf) {
    const __hip_bfloat16* pB = lds + 32768 + buf * 16384;
#pragma unroll
    for (int nj = 0; nj < 2; ++nj)
#pragma unroll
      for (int kk = 0; kk < 2; ++kk) {
        int row = wn * 64 + 32 + nj * 16 + l15;
        brL[nj][kk] = *(const bf16x8*)(pB + row * 64 + (((kk * 4 + l4) ^ (row & 7)) << 3));
      }
  };

  // ---- prologue (template): 4 halves (tile0) ; vmcnt(4) ; 3 halves (tile1) ;
  //      vmcnt(6) -> tile0 fully landed ; barrier ----
  stageA(0, 0, kbeg); stageB(0, 0, kbeg); stageB(0, 1, kbeg); stageA(0, 1, kbeg);
  VMC(4);
  stageA(1, 0, kbeg + 64); stageB(1, 0, kbeg + 64); stageB(1, 1, kbeg + 64);
  VMC(6);
  BAR();

  // ---- main loop: iteration t handles K-tiles 2t (buf0) and 2t+1 (buf1) ----
  const int nit = nt >> 1;
  for (int t = 0; t < nit; ++t) {
    const bool fl = (t + 1 < nit);            // full staging this iter?
    const int kA = kbeg + (2 * t + 1) * 64;   // tile 2t+1 (AL stage)
    const int kB = kbeg + (2 * t + 2) * 64;   // tile 2t+2
    const int kC = kbeg + (2 * t + 3) * 64;   // tile 2t+3
    // p1: 12 reads; stage b1.AL <- tile 2t+1; lgkm8 hint (partial pre-drain)
    readAE(0); readBE(0);
    stageA(1, 1, kA);
    LGKM8();
    BAR(); LGKM0();
    P1(); MQ(0, 0, arE, brE); P0();
    BAR();
    // p2: 4 reads; stage b0.AE <- tile 2t+2
    readBL(0);
    if (fl) stageA(0, 0, kB);
    BAR(); LGKM0();
    P1(); MQ(0, 2, arE, brL); P0();
    BAR();
    // p3: 8 reads; stage b0.BE
    readAL(0);
    if (fl) stageB(0, 0, kB);
    BAR(); LGKM0();
    P1(); MQ(4, 0, arL, brE); P0();
    BAR();
    // p4: stage b0.BL; vmcnt -> tile 2t+1 fully landed
    if (fl) stageB(0, 1, kB);
    BAR();
    P1(); MQ(4, 2, arL, brL); P0();
    if (fl) { VMC(6); } else { VMC(0); }
    BAR();
    // p5: 12 reads (tile 2t+1); stage b0.AL <- tile 2t+2; lgkm8 hint
    readAE(1); readBE(1);
    if (fl) stageA(0, 1, kB);
    LGKM8();
    BAR(); LGKM0();
    P1(); MQ(0, 0, arE, brE); P0();
    BAR();
    // p6: 4 reads; stage b1.AE <- tile 2t+3
    readBL(1);
    if (fl) stageA(1, 0, kC);
    BAR(); LGKM0();
    P1(); MQ(0, 2, arE, brL); P0();
    BAR();
    // p7: 8 reads; stage b1.BE
    readAL(1);
    if (fl) stageB(1, 0, kC);
    BAR(); LGKM0();
    P1(); MQ(4, 0, arL, brE); P0();
    BAR();
    // p8: stage b1.BL; vmcnt -> tile 2t+2 fully landed
    if (fl) stageB(1, 1, kC);
    BAR();
    P1(); MQ(4, 2, arL, brL); P0();
    if (fl) VMC(6);
    BAR();
  }

  // epilogue: D[row=(l>>4)*4+r][col=l&15] per 16x16 frag (m89-verified layout)
  const long slab = (EPI == 4) ? (long)blockIdx.z * (long)(gridDim.x * 256) * N : 0;
#pragma unroll
  for (int mi = 0; mi < 8; ++mi) {
    const long gmb = m0 + wm * 128 + mi * 16 + l4 * 4;   // rows gmb..gmb+3 (same batch b)
    const int b = (int)(gmb >> 5);
#pragma unroll
    for (int nj = 0; nj < 4; ++nj) {
      const long gn = n0 + wn * 64 + nj * 16 + l15;
      if constexpr (EPI == 0) {
        const int p = (int)(gn >> 10), e = (int)(gn & 1023);
        const float bias = p0[(p << 10) + e];
        const float wpb = p1[(b << 3) + p];
#pragma unroll
        for (int r = 0; r < 4; ++r) {
          float v = fast_gelu(acc[mi][nj][r] + bias) * wpb;
          bfout[(gmb + r) * (long)N + gn] = __float2bfloat16(v);
        }
      } else if constexpr (EPI == 2) {
#pragma unroll
        for (int r = 0; r < 4; ++r)
          f32out[(gmb + r) * (long)N + gn] = acc[mi][nj][r];
      } else {
#pragma unroll
        for (int r = 0; r < 4; ++r)
          bfout[slab + (gmb + r) * (long)N + gn] = __float2bfloat16(acc[mi][nj][r]);
      }
    }
  }
}

// ---------- small kernels ----------
__global__ void cvt_bf16_k(const float* __restrict__ in, __hip_bfloat16* __restrict__ out, long n) {
  long i = ((long)blockIdx.x * blockDim.x + threadIdx.x) * 4;
  if (i >= n) return;
  float4 v = *(const float4*)(in + i);
  *(bf16x4s*)(out + i) = bf16x4s{__float2bfloat16(v.x), __float2bfloat16(v.y),
                                 __float2bfloat16(v.z), __float2bfloat16(v.w)};
}

// out[c*out_rs + p*out_bs + r] = bf16(in[p*in_bs + r*1024 + c]), tiles of 32x32
__global__ void tconv_k(const float* __restrict__ in, __hip_bfloat16* __restrict__ out,
                        long in_bs, long out_rs, long out_bs) {
  __shared__ float tile[32][33];
  int p = blockIdx.z;
  int r0 = blockIdx.y * 32, c0 = blockIdx.x * 32;
  int tx = threadIdx.x, ty = threadIdx.y;
#pragma unroll
  for (int i = 0; i < 32; i += 8)
    tile[ty + i][tx] = in[(long)p * in_bs + (long)(r0 + ty + i) * 1024 + c0 + tx];
  __syncthreads();
#pragma unroll
  for (int i = 0; i < 32; i += 8)
    out[(long)(c0 + ty + i) * out_rs + (long)p * out_bs + (r0 + tx)] =
        __float2bfloat16(tile[tx][ty + i]);
}

__global__ void embed_k(const int* __restrict__ x, const float* __restrict__ emb,
                        const float* __restrict__ pos, float* __restrict__ h,
                        __hip_bfloat16* __restrict__ hb, float* __restrict__ divp) {
  int row = blockIdx.x;          // b*32 + t
  int t = row & 31;
  int c = threadIdx.x * 4;
  long tok = x[row];
  float4 e = *(const float4*)(emb + tok * 1024 + c);
  float4 q = *(const float4*)(pos + (long)t * 1024 + c);
  float4 v{e.x + q.x, e.y + q.y, e.z + q.z, e.w + q.w};
  *(float4*)(h + (long)row * 1024 + c) = v;
  *(bf16x4s*)(hb + (long)row * 1024 + c) =
      bf16x4s{__float2bfloat16(v.x), __float2bfloat16(v.y),
              __float2bfloat16(v.z), __float2bfloat16(v.w)};
  if (row == 0 && threadIdx.x == 0) *divp = 0.f;
}

// fused: selector softmax (-> W[dep]) + wb2[b,:] = sum_p W[b,p]*b2[p,:]
__global__ void select_wb2_k(const float* __restrict__ h, const float* __restrict__ selw,
                             const float* __restrict__ selb, const float* __restrict__ gum,
                             const float* __restrict__ b2, float* __restrict__ W,
                             float* __restrict__ wb2, int dep) {
  int b = blockIdx.x, tid = threadIdx.x;
  int c = tid * 4;
  float4 s{0.f, 0.f, 0.f, 0.f};
  for (int t = 0; t < 32; ++t) {
    const float4 v = *(const float4*)(h + ((long)(b * 32 + t)) * 1024 + c);
    s.x += v.x; s.y += v.y; s.z += v.z; s.w += v.w;
  }
  float lp[8];
#pragma unroll
  for (int p = 0; p < 8; ++p) {
    const float4 w = *(const float4*)(selw + dep * 8192 + p * 1024 + c);
    lp[p] = (s.x * w.x + s.y * w.y + s.z * w.z + s.w * w.w) * (1.f / 32.f);
  }
  int lane = tid & 63, wid = tid >> 6;
#pragma unroll
  for (int p = 0; p < 8; ++p)
    for (int o = 32; o; o >>= 1) lp[p] += __shfl_down(lp[p], o);
  __shared__ float red[4][8];
  __shared__ float wsm[8];
  if (lane == 0) {
#pragma unroll
    for (int p = 0; p < 8; ++p) red[wid][p] = lp[p];
  }
  __syncthreads();
  if (tid == 0) {
    float lg[8], mx = -1e30f;
    for (int p = 0; p < 8; ++p) {
      lg[p] = red[0][p] + red[1][p] + red[2][p] + red[3][p]
            + selb[dep * 8 + p] + gum[dep * 512 + b * 8 + p];
      mx = fmaxf(mx, lg[p]);
    }
    float sm = 0.f;
    for (int p = 0; p < 8; ++p) { lg[p] = expf(lg[p] - mx); sm += lg[p]; }
    float inv = 1.f / sm;
    for (int p = 0; p < 8; ++p) { wsm[p] = lg[p] * inv; W[dep * 512 + b * 8 + p] = lg[p] * inv; }
  }
  __syncthreads();
  float4 a{0.f, 0.f, 0.f, 0.f};
#pragma unroll
  for (int p = 0; p < 8; ++p) {
    float wp = wsm[p];
    const float4 v = *(const float4*)(b2 + p * 1024 + c);
    a.x += wp * v.x; a.y += wp * v.y; a.z += wp * v.z; a.w += wp * v.w;
  }
  *(float4*)(wb2 + (long)b * 1024 + c) = a;
}

// h += wb2 + sum_s part[s] (8 bf16 split-K slabs); write h f32 + bf16.
// 16B-vectorized: 8 elems/thread, 2 rows/block (256 thr). Block 0 also
// folds this depth's KL term into divp (wave-parallel).
__global__ void h_update_k(const __hip_bfloat16* __restrict__ part, float* __restrict__ h,
                           const float* __restrict__ wb2, __hip_bfloat16* __restrict__ hb,
                           const float* __restrict__ Wd, float* __restrict__ divp) {
  int row = blockIdx.x * 2 + (threadIdx.x >> 7);
  int c = (threadIdx.x & 127) * 8;
  long idx = (long)row * 1024 + c;
  float4 a0 = *(const float4*)(h + idx);
  float4 a1 = *(const float4*)(h + idx + 4);
  const float4 w0 = *(const float4*)(wb2 + (long)(row >> 5) * 1024 + c);
  const float4 w1 = *(const float4*)(wb2 + (long)(row >> 5) * 1024 + c + 4);
  a0.x += w0.x; a0.y += w0.y; a0.z += w0.z; a0.w += w0.w;
  a1.x += w1.x; a1.y += w1.y; a1.z += w1.z; a1.w += w1.w;
#pragma unroll
  for (int s = 0; s < 8; ++s) {
    const bf16x8 v = *(const bf16x8*)(part + (long)s * 2097152 + idx);
    a0.x += (float)v[0]; a0.y += (float)v[1]; a0.z += (float)v[2]; a0.w += (float)v[3];
    a1.x += (float)v[4]; a1.y += (float)v[5]; a1.z += (float)v[6]; a1.w += (float)v[7];
  }
  *(float4*)(h + idx) = a0;
  *(float4*)(h + idx + 4) = a1;
  bf16x8 ob;
  ob[0] = (__bf16)a0.x; ob[1] = (__bf16)a0.y; ob[2] = (__bf16)a0.z; ob[3] = (__bf16)a0.w;
  ob[4] = (__bf16)a1.x; ob[5] = (__bf16)a1.y; ob[6] = (__bf16)a1.z; ob[7] = (__bf16)a1.w;
  *(bf16x8*)(hb + idx) = ob;
  if (blockIdx.x == 0 && threadIdx.x < 64) {
    float w8[8];
#pragma unroll
    for (int p = 0; p < 8; ++p) w8[p] = Wd[threadIdx.x * 8 + p];
#pragma unroll
    for (int p = 0; p < 8; ++p)
      for (int o = 32; o; o >>= 1) w8[p] += __shfl_down(w8[p], o);
    if (threadIdx.x == 0) {
      float d = *divp;
      const float u = 0.125f, lu = logf(0.125f);
#pragma unroll
      for (int p = 0; p < 8; ++p) d += u * (lu - logf(w8[p] * (1.f / 64.f)));
      *divp = d;
    }
  }
}

__global__ void ln_k(const float* __restrict__ h, const float* __restrict__ g,
                     const float* __restrict__ be, __hip_bfloat16* __restrict__ hnb,
                     const float* __restrict__ divp, float* __restrict__ divout) {
  int row = blockIdx.x, tid = threadIdx.x;
  int c = tid * 4;
  const float4 v = *(const float4*)(h + (long)row * 1024 + c);
  float s = v.x + v.y + v.z + v.w;
  float q = v.x * v.x + v.y * v.y + v.z * v.z + v.w * v.w;
  for (int o = 32; o; o >>= 1) { s += __shfl_down(s, o); q += __shfl_down(q, o); }
  __shared__ float red[16];
  int lane = tid & 63, wid = tid >> 6;
  if (lane == 0) { red[wid] = s; red[8 + wid] = q; }
  __syncthreads();
  if (tid == 0) {
    float S = red[0] + red[1] + red[2] + red[3];
    float Q = red[8] + red[9] + red[10] + red[11];
    float mu = S * (1.f / 1024.f);
    float var = Q * (1.f / 1024.f) - mu * mu;
    red[0] = mu; red[1] = rsqrtf(var + 1e-5f);
  }
  __syncthreads();
  float mu = red[0], rs = red[1];
  float4 gg = *(const float4*)(g + c), bb = *(const float4*)(be + c);
  *(bf16x4s*)(hnb + (long)row * 1024 + c) =
      bf16x4s{__float2bfloat16((v.x - mu) * rs * gg.x + bb.x),
              __float2bfloat16((v.y - mu) * rs * gg.y + bb.y),
              __float2bfloat16((v.z - mu) * rs * gg.z + bb.z),
              __float2bfloat16((v.w - mu) * rs * gg.w + bb.w)};
  if (row == 0 && tid == 0) *divout = *divp;
}

// ---------- launch ----------
extern "C" void kernel_launch(void* const* d_in, const int* in_sizes, int n_in,
                              void* d_out, int out_size, void* d_ws, size_t ws_size,
                              hipStream_t stream) {
  (void)in_sizes; (void)n_in; (void)out_size; (void)ws_size;
  const int*   x     = (const int*)  d_in[0];
  const float* emb   = (const float*)d_in[1];
  const float* pos   = (const float*)d_in[2];
  const float* w1    = (const float*)d_in[3];
  const float* b1    = (const float*)d_in[4];
  const float* w2    = (const float*)d_in[5];
  const float* b2    = (const float*)d_in[6];
  const float* selw  = (const float*)d_in[7];
  const float* selb  = (const float*)d_in[8];
  const float* lng   = (const float*)d_in[9];
  const float* lnb   = (const float*)d_in[10];
  const float* headw = (const float*)d_in[11];
  const float* gum   = (const float*)d_in[12];
  float* out = (float*)d_out;

  char* ws = (char*)d_ws;
  __hip_bfloat16* w1t   = (__hip_bfloat16*)(ws);               // [8192,1024] bf16  16 MiB
  __hip_bfloat16* w2t   = (__hip_bfloat16*)(ws + 16777216);    // [1024,8192] bf16  16 MiB
  __hip_bfloat16* headb = (__hip_bfloat16*)(ws + 33554432);    // [32000,1024] bf16 62.5 MiB
  float*          h     = (float*)(ws + 99090432);             // [2048,1024] f32   8 MiB
  __hip_bfloat16* hb    = (__hip_bfloat16*)(ws + 107479040);   // [2048,1024] bf16  4 MiB
  __hip_bfloat16* u1    = (__hip_bfloat16*)(ws + 111673344);   // [2048,8192] bf16  32 MiB
  float*          Wall  = (float*)(ws + 145227776);            // [4,64,8]
  float*          wb2   = (float*)(ws + 145240064);            // [64,1024]
  float*          divp  = (float*)(ws + 145502208);            // scalar
  __hip_bfloat16* part  = (__hip_bfloat16*)out;  // GEMM2 bf16 partials: 8 x [2048,1024]
                                                 // = 32 MiB scratch inside d_out (262 MiB),
                                                 // overwritten by the head GEMM later

  cvt_bf16_k<<<32000, 256, 0, stream>>>(headw, headb, 32768000L);
  tconv_k<<<dim3(32, 32, 8), dim3(32, 8), 0, stream>>>(w1, w1t, 1L << 20, 1024L, 1L << 20);
  tconv_k<<<dim3(32, 32, 8), dim3(32, 8), 0, stream>>>(w2, w2t, 1L << 20, 8192L, 1024L);
  embed_k<<<2048, 256, 0, stream>>>(x, emb, pos, h, hb, divp);

  for (int d = 0; d < 4; ++d) {
    select_wb2_k<<<64, 256, 0, stream>>>(h, selw, selb, gum, b2, Wall, wb2, d);
    // u1' = W * gelu(h @ w1 + b1)   : M=2048 N=8192 K=1024  (8x32 = 256 blocks, 1/CU)
    gemm_nt<0><<<dim3(8, 32), 512, 0, stream>>>(hb, w1t, 1024, 1024, 8192, b1, Wall + d * 512, nullptr, u1);
    // partials[z] = bf16(u1' @ w2, K chunk z) : M=2048 N=1024 K=8192, split-K x8 (256 blocks)
    gemm_nt<4><<<dim3(8, 4, 8), 512, 0, stream>>>(u1, w2t, 8192, 1024, 1024, nullptr, nullptr, nullptr, part);
    h_update_k<<<1024, 256, 0, stream>>>(part, h, wb2, hb, Wall + d * 512, divp);
  }

  ln_k<<<2048, 256, 0, stream>>>(h, lng, lnb, hb, divp, out + 65536000L);
  // logits = hn @ head_w^T          : M=2048 N=32000 K=1024  (8x125 = 1000 blocks)
  gemm_nt<2><<<dim3(8, 125), 512, 0, stream>>>(hb, headb, 1024, 1024, 32000, nullptr, nullptr, out, nullptr);
}